// Round 8
// baseline (250.163 us; speedup 1.0000x reference)
//
#include <hip/hip_runtime.h>

#define HIDSZ 256
#define NAGENTS 8
#define NMODELS 64
#define NACTIONS 16
#define BN 256
#define IN_DIM 512
#define XDIM 768          // inp(512) + prev_hid(256)
#define COMMSZ 2048

// output flat offsets (f32 elements), return order: action, baseline, hid, comm
#define OUT_ACT 0
#define OUT_BASE (BN * NACTIONS)                    // 4096
#define OUT_HID (OUT_BASE + BN)                     // 4352
#define OUT_COMM (OUT_HID + BN * HIDSZ)             // 69888

// In-block row grouping: list of rows b with ids[b]==m (order irrelevant).
__device__ __forceinline__ int block_rows(const int* __restrict__ ids, int m,
                                          int* rows, int* cnt, int t) {
    if (t == 0) *cnt = 0;
    __syncthreads();
    int id = ids[t];                  // blockDim.x == BN == 256
    if (id == m) { int p = atomicAdd(cnt, 1); rows[p] = t; }
    __syncthreads();
    return *cnt;
}

// ---------------- K1: hid = relu(enc(inp) + rnn(prev_hid) + comm + biases) ----
// Block = (model m, col-quarter q): 64 cols. 4 waves = 4 reduction slices of
// the 768-dim (wave-uniform xs reads broadcast). Lane owns one col (scalar
// weight loads, 256B/wave-instr coalesced), 16-deep explicit pipeline,
// LDS cross-slice reduction. 256 blocks -> all CUs active.
__global__ __launch_bounds__(256) void k_hid(
    const float* __restrict__ inp, const float* __restrict__ prev_hid,
    const float* __restrict__ comm_in,
    const float* __restrict__ enc_w, const float* __restrict__ enc_b,
    const float* __restrict__ rnn_w, const float* __restrict__ rnn_b,
    const int* __restrict__ ids, float* __restrict__ out)
{
    int m = blockIdx.x, q = blockIdx.y;       // q: which 64-col quarter
    __shared__ int rows[BN];
    __shared__ int cnt;
    int t = threadIdx.x;
    int R = block_rows(ids, m, rows, &cnt, t);
    if (R == 0) return;

    __shared__ float xs[8][XDIM];             // 24 KB: 8 staged x-rows
    __shared__ float red[4][8][64];           // 8 KB: per-slice partials

    int lane = t & 63;
    int sl = t >> 6;                          // reduction slice == wave
    int col = q * 64 + lane;
    const float* ew = enc_w;                                   // [512][256]
    const float* rw = rnn_w + (size_t)m * HIDSZ * HIDSZ;       // [256][256]

    for (int g = 0; g * 8 < R; ++g) {
        __syncthreads();
        // stage 8 rows of x = [inp | prev_hid] as float4 (1536 float4)
        for (int j = t; j < 8 * 192; j += 256) {
            int r = j / 192, p = j % 192;
            int ri = g * 8 + r;
            float4 v = make_float4(0.f, 0.f, 0.f, 0.f);
            if (ri < R) {
                int b = rows[ri];
                v = (p < 128) ? ((const float4*)(inp + (size_t)b * IN_DIM))[p]
                              : ((const float4*)(prev_hid + (size_t)b * HIDSZ))[p - 128];
            }
            ((float4*)xs)[j] = v;
        }
        __syncthreads();

        float a[8];
        #pragma unroll
        for (int r = 0; r < 8; ++r) a[r] = 0.f;

        int ibase = sl * 192;                 // this wave's i-range
        for (int i0 = 0; i0 < 192; i0 += 16) {
            float wv[16];
            #pragma unroll
            for (int u = 0; u < 16; ++u) {
                int i = ibase + i0 + u;
                wv[u] = (i < IN_DIM) ? ew[(size_t)i * HIDSZ + col]
                                     : rw[(size_t)(i - IN_DIM) * HIDSZ + col];
            }
            #pragma unroll
            for (int u = 0; u < 16; ++u) {
                int i = ibase + i0 + u;
                #pragma unroll
                for (int r = 0; r < 8; ++r)
                    a[r] += xs[r][i] * wv[u];   // xs: wave-uniform broadcast
            }
        }
        #pragma unroll
        for (int r = 0; r < 8; ++r) red[sl][r][lane] = a[r];
        __syncthreads();

        // epilogue: 8 rows x 64 cols = 512 items, 2 per thread
        for (int j = t; j < 512; j += 256) {
            int r = j >> 6, l = j & 63;
            int ri = g * 8 + r;
            if (ri < R) {
                int b = rows[ri];
                int c = q * 64 + l;
                float s = red[0][r][l] + red[1][r][l] + red[2][r][l] + red[3][r][l];
                float cs = 0.f;
                #pragma unroll
                for (int a8 = 0; a8 < NAGENTS; ++a8)
                    cs += comm_in[((size_t)b * NAGENTS + a8) * HIDSZ + c];
                s += cs + enc_b[c] + rnn_b[m * HIDSZ + c];
                out[OUT_HID + (size_t)b * HIDSZ + c] = fmaxf(s, 0.f);
            }
        }
    }
}

// ---------------- K2: comm_out (y<8) + act softmax / baseline (y==8) ----------
__global__ __launch_bounds__(256) void k_out(
    const float* __restrict__ act_w, const float* __restrict__ act_b,
    const float* __restrict__ base_w, const float* __restrict__ base_b,
    const float* __restrict__ comm_w, const float* __restrict__ comm_b,
    const int* __restrict__ ids, float* __restrict__ out)
{
    int m = blockIdx.x, y = blockIdx.y;
    __shared__ int rows[BN];
    __shared__ int cnt;
    int t = threadIdx.x;
    int R = block_rows(ids, m, rows, &cnt, t);
    if (R == 0) return;
    const float* hid = out + OUT_HID;
    __shared__ float hs[16][HIDSZ];   // 16 KB (act path uses 16 rows, comm 8)

    if (y == 8) {
        if (blockIdx.z != 0) return;
        const float* aw = act_w + m * HIDSZ * NACTIONS;
        const float* bw = base_w + m * HIDSZ;
        for (int g = 0; g * 16 < R; ++g) {
            __syncthreads();
            for (int k = t; k < 16 * 64; k += 256) {   // stage 16 rows (float4)
                int rr = k >> 6, l = k & 63;
                int ri = g * 16 + rr;
                float4 v = make_float4(0.f, 0.f, 0.f, 0.f);
                if (ri < R) v = ((const float4*)(hid + (size_t)rows[ri] * HIDSZ))[l];
                ((float4*)hs)[rr * 64 + l] = v;
            }
            __syncthreads();
            {   // action probs: 16 row slots x 16 actions
                int o = t & 15, rs = t >> 4;
                int ri = g * 16 + rs;
                if (ri < R) {
                    int b = rows[ri];
                    float acc = act_b[m * NACTIONS + o];
                    #pragma unroll 8
                    for (int i = 0; i < HIDSZ; ++i)
                        acc += hs[rs][i] * aw[i * NACTIONS + o];
                    float mx = acc;
                    #pragma unroll
                    for (int d = 1; d < 16; d <<= 1) mx = fmaxf(mx, __shfl_xor(mx, d, 64));
                    float ex = __expf(acc - mx);
                    float sm = ex;
                    #pragma unroll
                    for (int d = 1; d < 16; d <<= 1) sm += __shfl_xor(sm, d, 64);
                    out[OUT_ACT + b * NACTIONS + o] = ex / sm;
                }
            }
            {   // baseline: one wave per row
                int lane = t & 63, w = t >> 6;
                for (int rr = w; rr < 16; rr += 4) {
                    int ri = g * 16 + rr;
                    if (ri < R) {
                        int b = rows[ri];
                        float p = 0.f;
                        #pragma unroll
                        for (int i = lane; i < HIDSZ; i += 64)
                            p += hs[rr][i] * bw[i];
                        #pragma unroll
                        for (int d = 1; d < 64; d <<= 1) p += __shfl_xor(p, d, 64);
                        if (lane == 0) out[OUT_BASE + b] = p + base_b[m];
                    }
                }
            }
        }
        return;
    }

    // ---- comm_out: col-eighth y (256 cols), 1 col/thread (scalar loads,
    //      1KB/block-instr coalesced), 8-row groups (z), 16-deep pipeline ----
    int c = y * 256 + t;
    const float* cw = comm_w + (size_t)m * HIDSZ * COMMSZ;
    float cb = comm_b[(size_t)m * COMMSZ + c];

    for (int g = blockIdx.z; g * 8 < R; g += gridDim.z) {
        __syncthreads();
        for (int k = t; k < 8 * 64; k += 256) {   // stage 8 rows (float4)
            int rr = k >> 6, l = k & 63;
            int ri = g * 8 + rr;
            float4 v = make_float4(0.f, 0.f, 0.f, 0.f);
            if (ri < R) v = ((const float4*)(hid + (size_t)rows[ri] * HIDSZ))[l];
            ((float4*)hs)[rr * 64 + l] = v;
        }
        __syncthreads();

        float acc[8];
        #pragma unroll
        for (int r = 0; r < 8; ++r) acc[r] = 0.f;

        for (int i0 = 0; i0 < HIDSZ; i0 += 16) {
            float wv[16];
            #pragma unroll
            for (int u = 0; u < 16; ++u)
                wv[u] = cw[(size_t)(i0 + u) * COMMSZ + c];
            #pragma unroll
            for (int u = 0; u < 16; ++u) {
                #pragma unroll
                for (int r = 0; r < 8; ++r)
                    acc[r] += hs[r][i0 + u] * wv[u];
            }
        }
        #pragma unroll
        for (int r = 0; r < 8; ++r) {
            int ri = g * 8 + r;
            if (ri < R) {
                int b = rows[ri];
                out[OUT_COMM + (size_t)b * COMMSZ + c] = acc[r] + cb;
            }
        }
    }
}

extern "C" void kernel_launch(void* const* d_in, const int* in_sizes, int n_in,
                              void* d_out, int out_size, void* d_ws, size_t ws_size,
                              hipStream_t stream) {
    const float* inp      = (const float*)d_in[0];
    const float* prev_hid = (const float*)d_in[1];
    const float* comm_in  = (const float*)d_in[2];
    const int*   ids      = (const int*)d_in[3];
    const float* enc_w    = (const float*)d_in[4];
    const float* enc_b    = (const float*)d_in[5];
    const float* rnn_w    = (const float*)d_in[6];
    const float* rnn_b    = (const float*)d_in[7];
    const float* act_w    = (const float*)d_in[8];
    const float* act_b    = (const float*)d_in[9];
    const float* base_w   = (const float*)d_in[10];
    const float* base_b   = (const float*)d_in[11];
    const float* comm_w   = (const float*)d_in[12];
    const float* comm_b   = (const float*)d_in[13];
    float* out = (float*)d_out;

    hipLaunchKernelGGL(k_hid, dim3(64, 4), dim3(256), 0, stream,
                       inp, prev_hid, comm_in, enc_w, enc_b, rnn_w, rnn_b,
                       ids, out);
    hipLaunchKernelGGL(k_out, dim3(64, 9, 2), dim3(256), 0, stream,
                       act_w, act_b, base_w, base_b, comm_w, comm_b,
                       ids, out);
}